// Round 4
// baseline (466.492 us; speedup 1.0000x reference)
//
#include <hip/hip_runtime.h>
#include <hip/hip_bf16.h>
#include <cstdint>
#include <cstddef>

// Problem constants
#define BB 4
#define SS 2048
#define DD 1024
#define HH 16
#define HDD 64

typedef __bf16 bf16_t;
typedef __bf16 bf16x8 __attribute__((ext_vector_type(8)));
typedef float f32x4 __attribute__((ext_vector_type(4)));
typedef unsigned u32x2 __attribute__((ext_vector_type(2)));

__device__ __forceinline__ unsigned short f2bf(float f) {
    unsigned u = __float_as_uint(f);
    unsigned r = (u + 0x7FFFu + ((u >> 16) & 1u)) >> 16;
    return (unsigned short)r;
}
__device__ __forceinline__ bf16_t f2bf16(float f) {
    return __builtin_bit_cast(bf16_t, f2bf(f));
}
__device__ __forceinline__ bf16x8 cvt8(float4 a, float4 b) {
    bf16x8 r;
    r[0] = f2bf16(a.x); r[1] = f2bf16(a.y);
    r[2] = f2bf16(a.z); r[3] = f2bf16(a.w);
    r[4] = f2bf16(b.x); r[5] = f2bf16(b.y);
    r[6] = f2bf16(b.z); r[7] = f2bf16(b.w);
    return r;
}
// packed f32x2 -> bf16x2 (RNE), lo16 = bf16(lo), hi16 = bf16(hi)
__device__ __forceinline__ unsigned cvtpk_bf16(float lo, float hi) {
    unsigned r;
    asm("v_cvt_pk_bf16_f32 %0, %1, %2" : "=v"(r) : "v"(lo), "v"(hi));
    return r;
}
// raw HW exp2: skips libm's denorm-guard sequence. 2^(-1e30) -> 0 in HW.
__device__ __forceinline__ float exp2_raw(float x) {
    float r;
    asm("v_exp_f32 %0, %1" : "=v"(r) : "v"(x));
    return r;
}

// async global->LDS, 16B per lane; LDS dest = wave-uniform base + lane*16
#define GLL16(gp, lp)                                                          \
    __builtin_amdgcn_global_load_lds(                                          \
        (const __attribute__((address_space(1))) void*)(gp),                   \
        (__attribute__((address_space(3))) void*)(lp), 16, 0, 0)

// ---------------------------------------------------------------------------
// fp32 -> bf16 converters (memory-bound, one-shot)
// ---------------------------------------------------------------------------
__global__ __launch_bounds__(256) void cvt1(const float* __restrict__ in,
                                            bf16_t* __restrict__ out) {
    size_t i = (size_t)blockIdx.x * 256 + threadIdx.x;
    const float4* p = (const float4*)in + i * 2;
    *(bf16x8*)(out + i * 8) = cvt8(p[0], p[1]);
}
__global__ __launch_bounds__(256) void cvt4(
    const float* __restrict__ w0, const float* __restrict__ w1,
    const float* __restrict__ w2, const float* __restrict__ w3,
    bf16_t* __restrict__ o0, bf16_t* __restrict__ o1,
    bf16_t* __restrict__ o2, bf16_t* __restrict__ o3) {
    const float* in = blockIdx.y == 0 ? w0 : blockIdx.y == 1 ? w1
                    : blockIdx.y == 2 ? w2 : w3;
    bf16_t* out = blockIdx.y == 0 ? o0 : blockIdx.y == 1 ? o1
                : blockIdx.y == 2 ? o2 : o3;
    size_t i = (size_t)blockIdx.x * 256 + threadIdx.x;
    const float4* p = (const float4*)in + i * 2;
    *(bf16x8*)(out + i * 8) = cvt8(p[0], p[1]);
}

// ---------------------------------------------------------------------------
// Fused QKV projection: C(8192x3072) = xb(8192x1024) @ [wq;wk;wv]^T.
// wb0..wb2 are contiguous -> single W with 3072 rows. Per-block sub-mode
// decoded block-uniformly from n0>>10: 0=Q (RoPE, qscale), 1=K (RoPE, 1.0),
// 2=V (transposed write). m97 staging pattern, grid (24,64) = 1536 blocks
// (vs 3x512): better CU fill, one launch ramp instead of three.
// ---------------------------------------------------------------------------
__global__ __launch_bounds__(256, 2) void gemm_qkv(
    const bf16_t* __restrict__ A, const bf16_t* __restrict__ Wall,
    bf16_t* __restrict__ Qb, bf16_t* __restrict__ Kb,
    bf16_t* __restrict__ Vt,
    const float* __restrict__ fcos, const float* __restrict__ fsin,
    float qscale)
{
    constexpr int K = 1024;
    __shared__ alignas(16) bf16_t lA[128 * 64];
    __shared__ alignas(16) bf16_t lB[128 * 64];

    const int tid  = threadIdx.x;
    const int w    = tid >> 6;
    const int lane = tid & 63;
    const int quad = lane >> 4;
    const int l16  = lane & 15;
    const int wm   = w >> 1;
    const int wn   = w & 1;
    const int m0   = blockIdx.y * 128;
    const int n0   = blockIdx.x * 128;   // 0..2944 over the stacked weights
    const int sub  = n0 >> 10;           // 0=Q, 1=K, 2=V (block-uniform)

    f32x4 acc[4][4];
#pragma unroll
    for (int i = 0; i < 4; i++)
#pragma unroll
        for (int j = 0; j < 4; j++) acc[i][j] = (f32x4){0.f, 0.f, 0.f, 0.f};

    const int srow8 = lane >> 3;
    const int slot  = lane & 7;

    for (int k0 = 0; k0 < K; k0 += 64) {
#pragma unroll
        for (int i = 0; i < 4; ++i) {
            int row = w * 32 + i * 8;
            GLL16(A + (size_t)(m0 + row + srow8) * K + k0 + slot * 8,
                  &lA[row * 64]);
            GLL16(Wall + (size_t)(n0 + row + srow8) * K + k0 + slot * 8,
                  &lB[row * 64]);
        }
        __syncthreads();
#pragma unroll
        for (int kk = 0; kk < 2; ++kk) {
            bf16x8 af[4], bfr[4];
#pragma unroll
            for (int mt = 0; mt < 4; ++mt)
                af[mt] = *(const bf16x8*)
                    &lA[(wm * 64 + mt * 16 + l16) * 64 + (kk * 4 + quad) * 8];
#pragma unroll
            for (int nt = 0; nt < 4; ++nt)
                bfr[nt] = *(const bf16x8*)
                    &lB[(wn * 64 + nt * 16 + l16) * 64 + (kk * 4 + quad) * 8];
#pragma unroll
            for (int mt = 0; mt < 4; ++mt)
#pragma unroll
                for (int nt = 0; nt < 4; ++nt)
                    acc[mt][nt] = __builtin_amdgcn_mfma_f32_16x16x32_bf16(
                        af[mt], bfr[nt], acc[mt][nt], 0, 0, 0);
        }
        __syncthreads();
    }

    if (sub < 2) {
        // RoPE + scale, write bf16 (B,H,S,HD)
        unsigned short* Cu = (unsigned short*)(sub == 0 ? Qb : Kb);
        const float scale = sub == 0 ? qscale : 1.0f;
#pragma unroll
        for (int mt = 0; mt < 4; ++mt) {
#pragma unroll
            for (int nt = 0; nt < 4; ++nt) {
                int col  = (n0 & 1023) + wn * 64 + nt * 16 + l16;
                int h    = col >> 6;
                int d    = col & 63;
                int pidx = d >> 1;
                bool even = (col & 1) == 0;
#pragma unroll
                for (int r = 0; r < 4; ++r) {
                    int m = m0 + wm * 64 + mt * 16 + quad * 4 + r;
                    int b = m >> 11;   // / S
                    int s = m & 2047;  // % S
                    float v  = acc[mt][nt][r];
                    float p  = __shfl_xor(v, 1);
                    float c  = fcos[s * 32 + pidx];
                    float sn = fsin[s * 32 + pidx];
                    float o  = even ? (v * c - p * sn) : (p * sn + v * c);
                    Cu[(size_t)((b * HH + h) * SS + s) * HDD + d] =
                        f2bf(o * scale);
                }
            }
        }
    } else {
        // V: write bf16 transposed (B,H,HD,S)
        unsigned short* Cu = (unsigned short*)Vt;
#pragma unroll
        for (int mt = 0; mt < 4; ++mt) {
#pragma unroll
            for (int nt = 0; nt < 4; ++nt) {
                int col = (n0 & 1023) + wn * 64 + nt * 16 + l16;
                int h = col >> 6, d = col & 63;
#pragma unroll
                for (int r = 0; r < 4; ++r) {
                    int m = m0 + wm * 64 + mt * 16 + quad * 4 + r;
                    int b = m >> 11, s = m & 2047;
                    Cu[(size_t)((b * HH + h) * HDD + d) * SS + s] =
                        f2bf(acc[mt][nt][r]);
                }
            }
        }
    }
}

// ---------------------------------------------------------------------------
// Final projection: C(MxN) = A(MxK) @ W^T, fp32 row-major output.
// ---------------------------------------------------------------------------
__global__ __launch_bounds__(256, 2) void gemm_out(
    const bf16_t* __restrict__ A, const bf16_t* __restrict__ W,
    float* __restrict__ Cf)
{
    constexpr int K = 1024, N = 1024;
    __shared__ alignas(16) bf16_t lA[128 * 64];
    __shared__ alignas(16) bf16_t lB[128 * 64];

    const int tid  = threadIdx.x;
    const int w    = tid >> 6;
    const int lane = tid & 63;
    const int quad = lane >> 4;
    const int l16  = lane & 15;
    const int wm   = w >> 1;
    const int wn   = w & 1;
    const int m0   = blockIdx.y * 128;
    const int n0   = blockIdx.x * 128;

    f32x4 acc[4][4];
#pragma unroll
    for (int i = 0; i < 4; i++)
#pragma unroll
        for (int j = 0; j < 4; j++) acc[i][j] = (f32x4){0.f, 0.f, 0.f, 0.f};

    const int srow8 = lane >> 3;
    const int slot  = lane & 7;

    for (int k0 = 0; k0 < K; k0 += 64) {
#pragma unroll
        for (int i = 0; i < 4; ++i) {
            int row = w * 32 + i * 8;
            GLL16(A + (size_t)(m0 + row + srow8) * K + k0 + slot * 8,
                  &lA[row * 64]);
            GLL16(W + (size_t)(n0 + row + srow8) * K + k0 + slot * 8,
                  &lB[row * 64]);
        }
        __syncthreads();
#pragma unroll
        for (int kk = 0; kk < 2; ++kk) {
            bf16x8 af[4], bfr[4];
#pragma unroll
            for (int mt = 0; mt < 4; ++mt)
                af[mt] = *(const bf16x8*)
                    &lA[(wm * 64 + mt * 16 + l16) * 64 + (kk * 4 + quad) * 8];
#pragma unroll
            for (int nt = 0; nt < 4; ++nt)
                bfr[nt] = *(const bf16x8*)
                    &lB[(wn * 64 + nt * 16 + l16) * 64 + (kk * 4 + quad) * 8];
#pragma unroll
            for (int mt = 0; mt < 4; ++mt)
#pragma unroll
                for (int nt = 0; nt < 4; ++nt)
                    acc[mt][nt] = __builtin_amdgcn_mfma_f32_16x16x32_bf16(
                        af[mt], bfr[nt], acc[mt][nt], 0, 0, 0);
        }
        __syncthreads();
    }

#pragma unroll
    for (int mt = 0; mt < 4; ++mt) {
        int mrow = m0 + wm * 64 + mt * 16 + quad * 4;
#pragma unroll
        for (int nt = 0; nt < 4; ++nt) {
            int col = n0 + wn * 64 + nt * 16 + l16;
#pragma unroll
            for (int r = 0; r < 4; ++r)
                Cf[(size_t)(mrow + r) * N + col] = acc[mt][nt][r];
        }
    }
}

// ---------------------------------------------------------------------------
// Flash attention v7 — LDS-shared K/V tiles, 1024 blocks (one 128-row
// super-tile per block). R3 was grid-capped at 2 blocks/CU (Occupancy 18%,
// no pipe >54%). Splitting the (T,15-T) pair doubles resident blocks to
// 4/CU (VGPR 84 <= 128, LDS 4x16KB <= 160KB). Heavy/light T interleaved in
// dispatch order so greedy CU-fill balances the causal wedge. Staging
// traffic is per-(bh,T), so L2-side demand is unchanged vs R3.
// VALU diet: raw v_exp_f32 (no libm denorm guard), causal mask hoisted
// under exec-skipped `if (diag)` (runs 1 of ~17 iters instead of all).
// In-register softmax/P-transpose (cvt_pk + permlane) unchanged.
// ---------------------------------------------------------------------------
__global__ __launch_bounds__(256, 4) void attn(
    const bf16_t* __restrict__ Q, const bf16_t* __restrict__ Kt,
    const bf16_t* __restrict__ Vt, bf16_t* __restrict__ O)
{
    __shared__ alignas(16) bf16_t lK[64 * 64];  // 8 KiB, k-row x hd
    __shared__ alignas(16) bf16_t lV[64 * 64];  // 8 KiB, hd   x k-col

    const int tid  = threadIdx.x;
    const int w    = tid >> 6;
    const int lane = tid & 63;
    const int quad = lane >> 4;
    const int l16  = lane & 15;

    // XCD-affinity decode: all 16 blocks of a given bh land on XCD bh&7.
    // j interleaves heavy/light super-tiles: T = {15,0,14,1,...} so the
    // dispatch stream mixes 32-iter and 2-iter blocks.
    const int blk  = blockIdx.x;          // 0..1023
    const int xcd  = blk & 7;
    const int rest = blk >> 3;            // 0..127
    const int j    = rest & 15;           // 0..15
    const int bh   = ((rest >> 4) << 3) | xcd;
    const int T    = (j & 1) ? (j >> 1) : (15 - (j >> 1));

    const int b = bh >> 4, h = bh & 15;
    unsigned short* Ou = (unsigned short*)O;
    const bf16_t* Qb = Q  + (size_t)bh * SS * HDD;
    const bf16_t* Kb = Kt + (size_t)bh * SS * HDD;
    const bf16_t* Vb = Vt + (size_t)bh * HDD * SS;

    // staging geometry: wave w fills LDS rows [w*16, w*16+16) of both tiles,
    // two GLL16 each (8 rows/GLL). Source chunk is XOR-swizzled so that the
    // swizzled ds_read on the consume side sees the identity mapping.
    const int r0a = w * 16;
    const int r0b = w * 16 + 8;
    const int rra = r0a + (lane >> 3);          // LDS row this lane feeds
    const int rrb = r0b + (lane >> 3);
    const int sca = ((lane & 7) ^ (rra & 7)) * 8;  // swizzled elem offset
    const int scb = ((lane & 7) ^ (rrb & 7)) * 8;

    const int q0  = T * 128 + w * 32;      // this wave's 32 q-rows
    const int nkb = 2 * T + 2;             // block-shared k-block count

    // Q fragments (B-operand of swapped QK^T), direct global
    bf16x8 qf[2][2];
#pragma unroll
    for (int qs = 0; qs < 2; ++qs) {
        const bf16_t* qp =
            Qb + (size_t)(q0 + qs * 16 + l16) * HDD + quad * 8;
        qf[qs][0] = *(const bf16x8*)(qp);
        qf[qs][1] = *(const bf16x8*)(qp + 32);
    }

    f32x4 o[2][4];
    float ps[2];
#pragma unroll
    for (int qs = 0; qs < 2; ++qs) {
        ps[qs] = 0.f;
#pragma unroll
        for (int i = 0; i < 4; ++i) o[qs][i] = (f32x4){0.f, 0.f, 0.f, 0.f};
    }

    for (int ib = 0; ib < nkb; ++ib) {
        const int kb = ib * 64;

        // cooperative stage: K rows kb..kb+63 (128B rows, contiguous),
        // V rows d=0..63 (128B segments at column kb, stride SS)
        GLL16(Kb + (size_t)(kb + rra) * HDD + sca, &lK[r0a * 64]);
        GLL16(Kb + (size_t)(kb + rrb) * HDD + scb, &lK[r0b * 64]);
        GLL16(Vb + (size_t)rra * SS + kb + sca,    &lV[r0a * 64]);
        GLL16(Vb + (size_t)rrb * SS + kb + scb,    &lV[r0b * 64]);
        __syncthreads();   // vmcnt(0) drain + all waves' tiles ready

        if (kb < q0 + 32) {            // wave-uniform: skip fully-masked
            const bool diag = (kb + 63 > q0);

            // K fragments from LDS (swizzled read)
            bf16x8 kf[4][2];
#pragma unroll
            for (int nt = 0; nt < 4; ++nt) {
                const int row = nt * 16 + l16;
#pragma unroll
                for (int hf = 0; hf < 2; ++hf)
                    kf[nt][hf] = *(const bf16x8*)
                        &lK[row * 64 + (((hf * 4 + quad) ^ (row & 7)) * 8)];
            }
            // V fragments from LDS (swizzled read)
            bf16x8 vf[2][4];
#pragma unroll
            for (int kk = 0; kk < 2; ++kk)
#pragma unroll
                for (int nt = 0; nt < 4; ++nt) {
                    const int row = nt * 16 + l16;
                    vf[kk][nt] = *(const bf16x8*)
                        &lV[row * 64 + (((kk * 4 + quad) ^ (row & 7)) * 8)];
                }

            // scores (transposed) + exp + in-lane bf16 pack
            unsigned pk[4][2][2];
#pragma unroll
            for (int nt = 0; nt < 4; ++nt) {
                const int krow = kb + nt * 16 + quad * 4;
#pragma unroll
                for (int qs = 0; qs < 2; ++qs) {
                    f32x4 s = (f32x4){0.f, 0.f, 0.f, 0.f};
                    s = __builtin_amdgcn_mfma_f32_16x16x32_bf16(
                        kf[nt][0], qf[qs][0], s, 0, 0, 0);
                    s = __builtin_amdgcn_mfma_f32_16x16x32_bf16(
                        kf[nt][1], qf[qs][1], s, 0, 0, 0);
                    if (diag) {        // exec-skipped off the diagonal
                        const int qcol = q0 + qs * 16 + l16;
#pragma unroll
                        for (int r = 0; r < 4; ++r)
                            if (krow + r > qcol) s[r] = -1e30f;
                    }
                    float ev[4];
#pragma unroll
                    for (int r = 0; r < 4; ++r) {
                        float e = exp2_raw(s[r]);   // scaled via Q-fold
                        ps[qs] += e;
                        ev[r] = e;
                    }
                    pk[nt][qs][0] = cvtpk_bf16(ev[0], ev[1]);
                    pk[nt][qs][1] = cvtpk_bf16(ev[2], ev[3]);
                }
            }

            // register-only P-transpose + PV accumulation
#pragma unroll
            for (int kk = 0; kk < 2; ++kk) {
#pragma unroll
                for (int qs = 0; qs < 2; ++qs) {
                    u32x2 sA = __builtin_amdgcn_permlane32_swap(
                        pk[2 * kk][qs][0], pk[2 * kk + 1][qs][0],
                        false, false);
                    u32x2 sB = __builtin_amdgcn_permlane32_swap(
                        pk[2 * kk][qs][1], pk[2 * kk + 1][qs][1],
                        false, false);
                    u32x2 tA = __builtin_amdgcn_permlane16_swap(
                        sA.x, sA.y, false, false);
                    u32x2 tB = __builtin_amdgcn_permlane16_swap(
                        sB.x, sB.y, false, false);
                    union { unsigned d[4]; bf16x8 v; } pf;
                    pf.d[0] = tA.x;  // k-pair (0,1) of quad*8
                    pf.d[1] = tB.x;  // k-pair (2,3)
                    pf.d[2] = tA.y;  // k-pair (4,5)
                    pf.d[3] = tB.y;  // k-pair (6,7)
#pragma unroll
                    for (int nt = 0; nt < 4; ++nt)
                        o[qs][nt] = __builtin_amdgcn_mfma_f32_16x16x32_bf16(
                            pf.v, vf[kk][nt], o[qs][nt], 0, 0, 0);
                }
            }
        }
        __syncthreads();   // compute done before next iter's staging
    }

    // epilogue: quad-reduce row sums, redistribute, O/l, write bf16
#pragma unroll
    for (int qs = 0; qs < 2; ++qs) {
        float tsum = ps[qs];
        tsum += __shfl_xor(tsum, 16);
        tsum += __shfl_xor(tsum, 32);
        // every lane now holds rowsum(q = q0+qs*16+l16)
        float inv[4];
#pragma unroll
        for (int r = 0; r < 4; ++r)
            inv[r] = 1.0f / __shfl(tsum, quad * 4 + r);
#pragma unroll
        for (int nt = 0; nt < 4; ++nt) {
            int d = nt * 16 + l16;
#pragma unroll
            for (int r = 0; r < 4; ++r) {
                int s = q0 + qs * 16 + quad * 4 + r;
                Ou[(size_t)(b * SS + s) * DD + h * HDD + d] =
                    f2bf(o[qs][nt][r] * inv[r]);
            }
        }
    }
}

// ---------------------------------------------------------------------------
// Buffer plan.  TSZ = B*S*D bf16 = 16 MiB; WSZ = D*D bf16 = 2 MiB.
//   d_out (32 MiB fp32): [0,TSZ) = xb, [TSZ,2*TSZ) = Vt — both dead before
//     the final GEMM overwrites d_out (it reads only Ob, wb3).
//   ws: Qb | Kb | Ob | wb0..3 = 56 MiB.  wb0..wb2 contiguous = stacked QKV W.
// ---------------------------------------------------------------------------
extern "C" void kernel_launch(void* const* d_in, const int* in_sizes, int n_in,
                              void* d_out, int out_size, void* d_ws,
                              size_t ws_size, hipStream_t stream)
{
    const float* x    = (const float*)d_in[0];
    const float* fcos = (const float*)d_in[1];
    const float* fsin = (const float*)d_in[2];
    const float* wq   = (const float*)d_in[3];
    const float* wk   = (const float*)d_in[4];
    const float* wv   = (const float*)d_in[5];
    const float* wo   = (const float*)d_in[6];

    char* ws = (char*)d_ws;
    const size_t TSZ = (size_t)BB * SS * DD * sizeof(bf16_t);  // 16 MiB
    const size_t WSZ = (size_t)DD * DD * sizeof(bf16_t);       // 2 MiB
    bf16_t* Qb  = (bf16_t*)(ws);
    bf16_t* Kb  = (bf16_t*)(ws + TSZ);
    bf16_t* Ob  = (bf16_t*)(ws + 2 * TSZ);
    bf16_t* wb0 = (bf16_t*)(ws + 3 * TSZ);
    bf16_t* wb1 = (bf16_t*)(ws + 3 * TSZ + WSZ);
    bf16_t* wb2 = (bf16_t*)(ws + 3 * TSZ + 2 * WSZ);
    bf16_t* wb3 = (bf16_t*)(ws + 3 * TSZ + 3 * WSZ);
    bf16_t* xb  = (bf16_t*)d_out;
    bf16_t* Vt  = (bf16_t*)((char*)d_out + TSZ);

    dim3 bb(256);
    cvt1<<<dim3(4096), bb, 0, stream>>>(x, xb);
    cvt4<<<dim3(512, 4), bb, 0, stream>>>(wq, wk, wv, wo, wb0, wb1, wb2, wb3);

    const float sscale = 0.125f * 1.44269504088896f;  // 1/sqrt(64)*log2(e)
    gemm_qkv<<<dim3(24, 64), bb, 0, stream>>>(xb, wb0, Qb, Kb, Vt,
                                              fcos, fsin, sscale);
    attn<<<dim3(1024), bb, 0, stream>>>(Qb, Kb, Vt, Ob);
    gemm_out<<<dim3(8, 64), bb, 0, stream>>>(Ob, wb3, (float*)d_out);
}

// Round 5
// 276.824 us; speedup vs baseline: 1.6852x; 1.6852x over previous
//
#include <hip/hip_runtime.h>
#include <hip/hip_bf16.h>
#include <cstdint>
#include <cstddef>

// Problem constants
#define BB 4
#define SS 2048
#define DD 1024
#define HH 16
#define HDD 64

typedef __bf16 bf16_t;
typedef __bf16 bf16x8 __attribute__((ext_vector_type(8)));
typedef float f32x4 __attribute__((ext_vector_type(4)));
typedef unsigned u32x2 __attribute__((ext_vector_type(2)));

__device__ __forceinline__ unsigned short f2bf(float f) {
    unsigned u = __float_as_uint(f);
    unsigned r = (u + 0x7FFFu + ((u >> 16) & 1u)) >> 16;
    return (unsigned short)r;
}
__device__ __forceinline__ bf16_t f2bf16(float f) {
    return __builtin_bit_cast(bf16_t, f2bf(f));
}
__device__ __forceinline__ bf16x8 cvt8(float4 a, float4 b) {
    bf16x8 r;
    r[0] = f2bf16(a.x); r[1] = f2bf16(a.y);
    r[2] = f2bf16(a.z); r[3] = f2bf16(a.w);
    r[4] = f2bf16(b.x); r[5] = f2bf16(b.y);
    r[6] = f2bf16(b.z); r[7] = f2bf16(b.w);
    return r;
}
// packed f32x2 -> bf16x2 (RNE), lo16 = bf16(lo), hi16 = bf16(hi)
__device__ __forceinline__ unsigned cvtpk_bf16(float lo, float hi) {
    unsigned r;
    asm("v_cvt_pk_bf16_f32 %0, %1, %2" : "=v"(r) : "v"(lo), "v"(hi));
    return r;
}
// raw HW exp2: skips libm's denorm-guard sequence. 2^(-1e30) -> 0 in HW.
__device__ __forceinline__ float exp2_raw(float x) {
    float r;
    asm("v_exp_f32 %0, %1" : "=v"(r) : "v"(x));
    return r;
}

// async global->LDS, 16B per lane; LDS dest = wave-uniform base + lane*16
#define GLL16(gp, lp)                                                          \
    __builtin_amdgcn_global_load_lds(                                          \
        (const __attribute__((address_space(1))) void*)(gp),                   \
        (__attribute__((address_space(3))) void*)(lp), 16, 0, 0)

// ---------------------------------------------------------------------------
// fp32 -> bf16 converters (memory-bound, one-shot)
// ---------------------------------------------------------------------------
__global__ __launch_bounds__(256) void cvt1(const float* __restrict__ in,
                                            bf16_t* __restrict__ out) {
    size_t i = (size_t)blockIdx.x * 256 + threadIdx.x;
    const float4* p = (const float4*)in + i * 2;
    *(bf16x8*)(out + i * 8) = cvt8(p[0], p[1]);
}
__global__ __launch_bounds__(256) void cvt4(
    const float* __restrict__ w0, const float* __restrict__ w1,
    const float* __restrict__ w2, const float* __restrict__ w3,
    bf16_t* __restrict__ o0, bf16_t* __restrict__ o1,
    bf16_t* __restrict__ o2, bf16_t* __restrict__ o3) {
    const float* in = blockIdx.y == 0 ? w0 : blockIdx.y == 1 ? w1
                    : blockIdx.y == 2 ? w2 : w3;
    bf16_t* out = blockIdx.y == 0 ? o0 : blockIdx.y == 1 ? o1
                : blockIdx.y == 2 ? o2 : o3;
    size_t i = (size_t)blockIdx.x * 256 + threadIdx.x;
    const float4* p = (const float4*)in + i * 2;
    *(bf16x8*)(out + i * 8) = cvt8(p[0], p[1]);
}

// ---------------------------------------------------------------------------
// Fused QKV projection: C(8192x3072) = xb(8192x1024) @ [wq;wk;wv]^T.
// wb0..wb2 are contiguous -> single W with 3072 rows. Per-block sub-mode
// decoded block-uniformly from n0>>10: 0=Q (RoPE, qscale), 1=K (RoPE, 1.0),
// 2=V (transposed write). m97 staging pattern, grid (24,64) = 1536 blocks.
// ---------------------------------------------------------------------------
__global__ __launch_bounds__(256, 2) void gemm_qkv(
    const bf16_t* __restrict__ A, const bf16_t* __restrict__ Wall,
    bf16_t* __restrict__ Qb, bf16_t* __restrict__ Kb,
    bf16_t* __restrict__ Vt,
    const float* __restrict__ fcos, const float* __restrict__ fsin,
    float qscale)
{
    constexpr int K = 1024;
    __shared__ alignas(16) bf16_t lA[128 * 64];
    __shared__ alignas(16) bf16_t lB[128 * 64];

    const int tid  = threadIdx.x;
    const int w    = tid >> 6;
    const int lane = tid & 63;
    const int quad = lane >> 4;
    const int l16  = lane & 15;
    const int wm   = w >> 1;
    const int wn   = w & 1;
    const int m0   = blockIdx.y * 128;
    const int n0   = blockIdx.x * 128;   // 0..2944 over the stacked weights
    const int sub  = n0 >> 10;           // 0=Q, 1=K, 2=V (block-uniform)

    f32x4 acc[4][4];
#pragma unroll
    for (int i = 0; i < 4; i++)
#pragma unroll
        for (int j = 0; j < 4; j++) acc[i][j] = (f32x4){0.f, 0.f, 0.f, 0.f};

    const int srow8 = lane >> 3;
    const int slot  = lane & 7;

    for (int k0 = 0; k0 < K; k0 += 64) {
#pragma unroll
        for (int i = 0; i < 4; ++i) {
            int row = w * 32 + i * 8;
            GLL16(A + (size_t)(m0 + row + srow8) * K + k0 + slot * 8,
                  &lA[row * 64]);
            GLL16(Wall + (size_t)(n0 + row + srow8) * K + k0 + slot * 8,
                  &lB[row * 64]);
        }
        __syncthreads();
#pragma unroll
        for (int kk = 0; kk < 2; ++kk) {
            bf16x8 af[4], bfr[4];
#pragma unroll
            for (int mt = 0; mt < 4; ++mt)
                af[mt] = *(const bf16x8*)
                    &lA[(wm * 64 + mt * 16 + l16) * 64 + (kk * 4 + quad) * 8];
#pragma unroll
            for (int nt = 0; nt < 4; ++nt)
                bfr[nt] = *(const bf16x8*)
                    &lB[(wn * 64 + nt * 16 + l16) * 64 + (kk * 4 + quad) * 8];
#pragma unroll
            for (int mt = 0; mt < 4; ++mt)
#pragma unroll
                for (int nt = 0; nt < 4; ++nt)
                    acc[mt][nt] = __builtin_amdgcn_mfma_f32_16x16x32_bf16(
                        af[mt], bfr[nt], acc[mt][nt], 0, 0, 0);
        }
        __syncthreads();
    }

    if (sub < 2) {
        // RoPE + scale, write bf16 (B,H,S,HD)
        unsigned short* Cu = (unsigned short*)(sub == 0 ? Qb : Kb);
        const float scale = sub == 0 ? qscale : 1.0f;
#pragma unroll
        for (int mt = 0; mt < 4; ++mt) {
#pragma unroll
            for (int nt = 0; nt < 4; ++nt) {
                int col  = (n0 & 1023) + wn * 64 + nt * 16 + l16;
                int h    = col >> 6;
                int d    = col & 63;
                int pidx = d >> 1;
                bool even = (col & 1) == 0;
#pragma unroll
                for (int r = 0; r < 4; ++r) {
                    int m = m0 + wm * 64 + mt * 16 + quad * 4 + r;
                    int b = m >> 11;   // / S
                    int s = m & 2047;  // % S
                    float v  = acc[mt][nt][r];
                    float p  = __shfl_xor(v, 1);
                    float c  = fcos[s * 32 + pidx];
                    float sn = fsin[s * 32 + pidx];
                    float o  = even ? (v * c - p * sn) : (p * sn + v * c);
                    Cu[(size_t)((b * HH + h) * SS + s) * HDD + d] =
                        f2bf(o * scale);
                }
            }
        }
    } else {
        // V: write bf16 transposed (B,H,HD,S)
        unsigned short* Cu = (unsigned short*)Vt;
#pragma unroll
        for (int mt = 0; mt < 4; ++mt) {
#pragma unroll
            for (int nt = 0; nt < 4; ++nt) {
                int col = (n0 & 1023) + wn * 64 + nt * 16 + l16;
                int h = col >> 6, d = col & 63;
#pragma unroll
                for (int r = 0; r < 4; ++r) {
                    int m = m0 + wm * 64 + mt * 16 + quad * 4 + r;
                    int b = m >> 11, s = m & 2047;
                    Cu[(size_t)((b * HH + h) * HDD + d) * SS + s] =
                        f2bf(acc[mt][nt][r]);
                }
            }
        }
    }
}

// ---------------------------------------------------------------------------
// Final projection: C(MxN) = A(MxK) @ W^T, fp32 row-major output.
// ---------------------------------------------------------------------------
__global__ __launch_bounds__(256, 2) void gemm_out(
    const bf16_t* __restrict__ A, const bf16_t* __restrict__ W,
    float* __restrict__ Cf)
{
    constexpr int K = 1024, N = 1024;
    __shared__ alignas(16) bf16_t lA[128 * 64];
    __shared__ alignas(16) bf16_t lB[128 * 64];

    const int tid  = threadIdx.x;
    const int w    = tid >> 6;
    const int lane = tid & 63;
    const int quad = lane >> 4;
    const int l16  = lane & 15;
    const int wm   = w >> 1;
    const int wn   = w & 1;
    const int m0   = blockIdx.y * 128;
    const int n0   = blockIdx.x * 128;

    f32x4 acc[4][4];
#pragma unroll
    for (int i = 0; i < 4; i++)
#pragma unroll
        for (int j = 0; j < 4; j++) acc[i][j] = (f32x4){0.f, 0.f, 0.f, 0.f};

    const int srow8 = lane >> 3;
    const int slot  = lane & 7;

    for (int k0 = 0; k0 < K; k0 += 64) {
#pragma unroll
        for (int i = 0; i < 4; ++i) {
            int row = w * 32 + i * 8;
            GLL16(A + (size_t)(m0 + row + srow8) * K + k0 + slot * 8,
                  &lA[row * 64]);
            GLL16(W + (size_t)(n0 + row + srow8) * K + k0 + slot * 8,
                  &lB[row * 64]);
        }
        __syncthreads();
#pragma unroll
        for (int kk = 0; kk < 2; ++kk) {
            bf16x8 af[4], bfr[4];
#pragma unroll
            for (int mt = 0; mt < 4; ++mt)
                af[mt] = *(const bf16x8*)
                    &lA[(wm * 64 + mt * 16 + l16) * 64 + (kk * 4 + quad) * 8];
#pragma unroll
            for (int nt = 0; nt < 4; ++nt)
                bfr[nt] = *(const bf16x8*)
                    &lB[(wn * 64 + nt * 16 + l16) * 64 + (kk * 4 + quad) * 8];
#pragma unroll
            for (int mt = 0; mt < 4; ++mt)
#pragma unroll
                for (int nt = 0; nt < 4; ++nt)
                    acc[mt][nt] = __builtin_amdgcn_mfma_f32_16x16x32_bf16(
                        af[mt], bfr[nt], acc[mt][nt], 0, 0, 0);
        }
        __syncthreads();
    }

#pragma unroll
    for (int mt = 0; mt < 4; ++mt) {
        int mrow = m0 + wm * 64 + mt * 16 + quad * 4;
#pragma unroll
        for (int nt = 0; nt < 4; ++nt) {
            int col = n0 + wn * 64 + nt * 16 + l16;
#pragma unroll
            for (int r = 0; r < 4; ++r)
                Cf[(size_t)(mrow + r) * N + col] = acc[mt][nt][r];
        }
    }
}

// ---------------------------------------------------------------------------
// Flash attention v8 — LDS-shared K/V tiles, 1024 blocks (one 128-row
// super-tile per block). R4 LESSON: __launch_bounds__(256,4) forced a
// 64-VGPR allocation -> massive scratch spill (WRITE_SIZE 427MB, 3x slower).
// Occupancy comes from the 1024-block grid + natural 84-VGPR fit (84 <= 128
// -> 4 waves/SIMD allowed); launch_bounds stays at (256,2) which the
// allocator handles without spilling. Heavy/light T interleaved in dispatch
// order so greedy CU-fill balances the causal wedge.
// VALU diet: raw v_exp_f32, causal mask under exec-skipped `if (diag)`.
// In-register softmax/P-transpose (cvt_pk + permlane) unchanged.
// ---------------------------------------------------------------------------
__global__ __launch_bounds__(256, 2) void attn(
    const bf16_t* __restrict__ Q, const bf16_t* __restrict__ Kt,
    const bf16_t* __restrict__ Vt, bf16_t* __restrict__ O)
{
    __shared__ alignas(16) bf16_t lK[64 * 64];  // 8 KiB, k-row x hd
    __shared__ alignas(16) bf16_t lV[64 * 64];  // 8 KiB, hd   x k-col

    const int tid  = threadIdx.x;
    const int w    = tid >> 6;
    const int lane = tid & 63;
    const int quad = lane >> 4;
    const int l16  = lane & 15;

    // XCD-affinity decode: all 16 blocks of a given bh land on XCD bh&7.
    // j interleaves heavy/light super-tiles: T = {15,0,14,1,...} so the
    // dispatch stream mixes 32-iter and 2-iter blocks.
    const int blk  = blockIdx.x;          // 0..1023
    const int xcd  = blk & 7;
    const int rest = blk >> 3;            // 0..127
    const int j    = rest & 15;           // 0..15
    const int bh   = ((rest >> 4) << 3) | xcd;
    const int T    = (j & 1) ? (j >> 1) : (15 - (j >> 1));

    const int b = bh >> 4, h = bh & 15;
    unsigned short* Ou = (unsigned short*)O;
    const bf16_t* Qb = Q  + (size_t)bh * SS * HDD;
    const bf16_t* Kb = Kt + (size_t)bh * SS * HDD;
    const bf16_t* Vb = Vt + (size_t)bh * HDD * SS;

    // staging geometry: wave w fills LDS rows [w*16, w*16+16) of both tiles,
    // two GLL16 each (8 rows/GLL). Source chunk is XOR-swizzled so that the
    // swizzled ds_read on the consume side sees the identity mapping.
    const int r0a = w * 16;
    const int r0b = w * 16 + 8;
    const int rra = r0a + (lane >> 3);          // LDS row this lane feeds
    const int rrb = r0b + (lane >> 3);
    const int sca = ((lane & 7) ^ (rra & 7)) * 8;  // swizzled elem offset
    const int scb = ((lane & 7) ^ (rrb & 7)) * 8;

    const int q0  = T * 128 + w * 32;      // this wave's 32 q-rows
    const int nkb = 2 * T + 2;             // block-shared k-block count

    // Q fragments (B-operand of swapped QK^T), direct global
    bf16x8 qf[2][2];
#pragma unroll
    for (int qs = 0; qs < 2; ++qs) {
        const bf16_t* qp =
            Qb + (size_t)(q0 + qs * 16 + l16) * HDD + quad * 8;
        qf[qs][0] = *(const bf16x8*)(qp);
        qf[qs][1] = *(const bf16x8*)(qp + 32);
    }

    f32x4 o[2][4];
    float ps[2];
#pragma unroll
    for (int qs = 0; qs < 2; ++qs) {
        ps[qs] = 0.f;
#pragma unroll
        for (int i = 0; i < 4; ++i) o[qs][i] = (f32x4){0.f, 0.f, 0.f, 0.f};
    }

    for (int ib = 0; ib < nkb; ++ib) {
        const int kb = ib * 64;

        // cooperative stage: K rows kb..kb+63 (128B rows, contiguous),
        // V rows d=0..63 (128B segments at column kb, stride SS)
        GLL16(Kb + (size_t)(kb + rra) * HDD + sca, &lK[r0a * 64]);
        GLL16(Kb + (size_t)(kb + rrb) * HDD + scb, &lK[r0b * 64]);
        GLL16(Vb + (size_t)rra * SS + kb + sca,    &lV[r0a * 64]);
        GLL16(Vb + (size_t)rrb * SS + kb + scb,    &lV[r0b * 64]);
        __syncthreads();   // vmcnt(0) drain + all waves' tiles ready

        if (kb < q0 + 32) {            // wave-uniform: skip fully-masked
            const bool diag = (kb + 63 > q0);

            // K fragments from LDS (swizzled read)
            bf16x8 kf[4][2];
#pragma unroll
            for (int nt = 0; nt < 4; ++nt) {
                const int row = nt * 16 + l16;
#pragma unroll
                for (int hf = 0; hf < 2; ++hf)
                    kf[nt][hf] = *(const bf16x8*)
                        &lK[row * 64 + (((hf * 4 + quad) ^ (row & 7)) * 8)];
            }
            // V fragments from LDS (swizzled read)
            bf16x8 vf[2][4];
#pragma unroll
            for (int kk = 0; kk < 2; ++kk)
#pragma unroll
                for (int nt = 0; nt < 4; ++nt) {
                    const int row = nt * 16 + l16;
                    vf[kk][nt] = *(const bf16x8*)
                        &lV[row * 64 + (((kk * 4 + quad) ^ (row & 7)) * 8)];
                }

            // scores (transposed) + exp + in-lane bf16 pack
            unsigned pk[4][2][2];
#pragma unroll
            for (int nt = 0; nt < 4; ++nt) {
                const int krow = kb + nt * 16 + quad * 4;
#pragma unroll
                for (int qs = 0; qs < 2; ++qs) {
                    f32x4 s = (f32x4){0.f, 0.f, 0.f, 0.f};
                    s = __builtin_amdgcn_mfma_f32_16x16x32_bf16(
                        kf[nt][0], qf[qs][0], s, 0, 0, 0);
                    s = __builtin_amdgcn_mfma_f32_16x16x32_bf16(
                        kf[nt][1], qf[qs][1], s, 0, 0, 0);
                    if (diag) {        // exec-skipped off the diagonal
                        const int qcol = q0 + qs * 16 + l16;
#pragma unroll
                        for (int r = 0; r < 4; ++r)
                            if (krow + r > qcol) s[r] = -1e30f;
                    }
                    float ev[4];
#pragma unroll
                    for (int r = 0; r < 4; ++r) {
                        float e = exp2_raw(s[r]);   // scaled via Q-fold
                        ps[qs] += e;
                        ev[r] = e;
                    }
                    pk[nt][qs][0] = cvtpk_bf16(ev[0], ev[1]);
                    pk[nt][qs][1] = cvtpk_bf16(ev[2], ev[3]);
                }
            }

            // register-only P-transpose + PV accumulation
#pragma unroll
            for (int kk = 0; kk < 2; ++kk) {
#pragma unroll
                for (int qs = 0; qs < 2; ++qs) {
                    u32x2 sA = __builtin_amdgcn_permlane32_swap(
                        pk[2 * kk][qs][0], pk[2 * kk + 1][qs][0],
                        false, false);
                    u32x2 sB = __builtin_amdgcn_permlane32_swap(
                        pk[2 * kk][qs][1], pk[2 * kk + 1][qs][1],
                        false, false);
                    u32x2 tA = __builtin_amdgcn_permlane16_swap(
                        sA.x, sA.y, false, false);
                    u32x2 tB = __builtin_amdgcn_permlane16_swap(
                        sB.x, sB.y, false, false);
                    union { unsigned d[4]; bf16x8 v; } pf;
                    pf.d[0] = tA.x;  // k-pair (0,1) of quad*8
                    pf.d[1] = tB.x;  // k-pair (2,3)
                    pf.d[2] = tA.y;  // k-pair (4,5)
                    pf.d[3] = tB.y;  // k-pair (6,7)
#pragma unroll
                    for (int nt = 0; nt < 4; ++nt)
                        o[qs][nt] = __builtin_amdgcn_mfma_f32_16x16x32_bf16(
                            pf.v, vf[kk][nt], o[qs][nt], 0, 0, 0);
                }
            }
        }
        __syncthreads();   // compute done before next iter's staging
    }

    // epilogue: quad-reduce row sums, redistribute, O/l, write bf16
#pragma unroll
    for (int qs = 0; qs < 2; ++qs) {
        float tsum = ps[qs];
        tsum += __shfl_xor(tsum, 16);
        tsum += __shfl_xor(tsum, 32);
        // every lane now holds rowsum(q = q0+qs*16+l16)
        float inv[4];
#pragma unroll
        for (int r = 0; r < 4; ++r)
            inv[r] = 1.0f / __shfl(tsum, quad * 4 + r);
#pragma unroll
        for (int nt = 0; nt < 4; ++nt) {
            int d = nt * 16 + l16;
#pragma unroll
            for (int r = 0; r < 4; ++r) {
                int s = q0 + qs * 16 + quad * 4 + r;
                Ou[(size_t)(b * SS + s) * DD + h * HDD + d] =
                    f2bf(o[qs][nt][r] * inv[r]);
            }
        }
    }
}

// ---------------------------------------------------------------------------
// Buffer plan.  TSZ = B*S*D bf16 = 16 MiB; WSZ = D*D bf16 = 2 MiB.
//   d_out (32 MiB fp32): [0,TSZ) = xb, [TSZ,2*TSZ) = Vt — both dead before
//     the final GEMM overwrites d_out (it reads only Ob, wb3).
//   ws: Qb | Kb | Ob | wb0..3 = 56 MiB.  wb0..wb2 contiguous = stacked QKV W.
// ---------------------------------------------------------------------------
extern "C" void kernel_launch(void* const* d_in, const int* in_sizes, int n_in,
                              void* d_out, int out_size, void* d_ws,
                              size_t ws_size, hipStream_t stream)
{
    const float* x    = (const float*)d_in[0];
    const float* fcos = (const float*)d_in[1];
    const float* fsin = (const float*)d_in[2];
    const float* wq   = (const float*)d_in[3];
    const float* wk   = (const float*)d_in[4];
    const float* wv   = (const float*)d_in[5];
    const float* wo   = (const float*)d_in[6];

    char* ws = (char*)d_ws;
    const size_t TSZ = (size_t)BB * SS * DD * sizeof(bf16_t);  // 16 MiB
    const size_t WSZ = (size_t)DD * DD * sizeof(bf16_t);       // 2 MiB
    bf16_t* Qb  = (bf16_t*)(ws);
    bf16_t* Kb  = (bf16_t*)(ws + TSZ);
    bf16_t* Ob  = (bf16_t*)(ws + 2 * TSZ);
    bf16_t* wb0 = (bf16_t*)(ws + 3 * TSZ);
    bf16_t* wb1 = (bf16_t*)(ws + 3 * TSZ + WSZ);
    bf16_t* wb2 = (bf16_t*)(ws + 3 * TSZ + 2 * WSZ);
    bf16_t* wb3 = (bf16_t*)(ws + 3 * TSZ + 3 * WSZ);
    bf16_t* xb  = (bf16_t*)d_out;
    bf16_t* Vt  = (bf16_t*)((char*)d_out + TSZ);

    dim3 bb(256);
    cvt1<<<dim3(4096), bb, 0, stream>>>(x, xb);
    cvt4<<<dim3(512, 4), bb, 0, stream>>>(wq, wk, wv, wo, wb0, wb1, wb2, wb3);

    const float sscale = 0.125f * 1.44269504088896f;  // 1/sqrt(64)*log2(e)
    gemm_qkv<<<dim3(24, 64), bb, 0, stream>>>(xb, wb0, Qb, Kb, Vt,
                                              fcos, fsin, sscale);
    attn<<<dim3(1024), bb, 0, stream>>>(Qb, Kb, Vt, Ob);
    gemm_out<<<dim3(8, 64), bb, 0, stream>>>(Ob, wb3, (float*)d_out);
}